// Round 6
// baseline (2560.837 us; speedup 1.0000x reference)
//
#include <hip/hip_runtime.h>
#include <hip/hip_bf16.h>

#define NPIX 16384   // 128*128
#define BATCH 4
#define DIM 256
#define HEADS 8
#define HD 32
#define CHQKV 768
#define HID 680
#define HID2 1360

typedef __attribute__((ext_vector_type(8))) short short8v;
typedef __attribute__((ext_vector_type(4))) float float4v;

__device__ __forceinline__ ushort bf_hi(float v) {
    unsigned u = __float_as_uint(v);
    u += 0x7fffu + ((u >> 16) & 1u);          // RNE to bf16
    return (ushort)(u >> 16);
}
__device__ __forceinline__ float bf_tof(ushort h) {
    return __uint_as_float(((unsigned)h) << 16);
}
__device__ __forceinline__ void bf_split(float v, ushort &h, ushort &l) {
    h = bf_hi(v);
    l = bf_hi(v - bf_tof(h));
}

__global__ void zero_kernel(float* __restrict__ p, int n) {
    int i = blockIdx.x * blockDim.x + threadIdx.x;
    if (i < n) p[i] = 0.f;
}

// ---- one-time: split all 4 weight matrices into bf16 hi/lo planes ([m][k] layout) ----
__global__ void convert_weights(const float* __restrict__ qkv_w, const float* __restrict__ po_w,
                                const float* __restrict__ pin_w, const float* __restrict__ pout_w,
                                ushort* __restrict__ qH, ushort* __restrict__ qL,
                                ushort* __restrict__ oH, ushort* __restrict__ oL,
                                ushort* __restrict__ iH, ushort* __restrict__ iL,
                                ushort* __restrict__ uH, ushort* __restrict__ uL) {
    int i = blockIdx.x * 256 + threadIdx.x;
    const float* s; ushort *dh, *dl; int off;
    if (i < 196608)      { s = qkv_w;  dh = qH; dl = qL; off = i; }
    else if (i < 262144) { s = po_w;   dh = oH; dl = oL; off = i - 196608; }
    else if (i < 610304) { s = pin_w;  dh = iH; dl = iL; off = i - 262144; }
    else if (i < 784384) { s = pout_w; dh = uH; dl = uL; off = i - 610304; }
    else return;
    ushort h, l; bf_split(s[off], h, l);
    dh[off] = h; dl[off] = l;
}

// ---- fused LN stats + apply, writing k-pair-interleaved bf16 hi/lo planes ----
__global__ void ln_fused(const float* __restrict__ x, const float* __restrict__ lw,
                         const float* __restrict__ lb, uint* __restrict__ XH,
                         uint* __restrict__ XL) {
    __shared__ float Ss[256], Ss2[256], muS[64], rsS[64], wS[256], bS[256];
    int t = threadIdx.x, px = t & 63, cg = t >> 6, c0 = cg * 64;
    int p = blockIdx.x * 64 + px;
    wS[t] = lw[t]; bS[t] = lb[t];
    float v[64]; float s = 0.f, s2 = 0.f;
    #pragma unroll
    for (int j = 0; j < 64; ++j) {
        v[j] = x[(size_t)(c0 + j) * NPIX + p];
        s += v[j]; s2 += v[j] * v[j];
    }
    Ss[t] = s; Ss2[t] = s2;
    __syncthreads();
    if (t < 64) {
        float ts = Ss[t] + Ss[t + 64] + Ss[t + 128] + Ss[t + 192];
        float t2 = Ss2[t] + Ss2[t + 64] + Ss2[t + 128] + Ss2[t + 192];
        float m = ts * (1.0f / DIM);
        float var = t2 * (1.0f / DIM) - m * m;
        muS[t] = m; rsS[t] = rsqrtf(var + 1e-5f);
    }
    __syncthreads();
    float m = muS[px], r = rsS[px];
    #pragma unroll
    for (int j = 0; j < 64; j += 2) {
        float a = (v[j] - m) * r * wS[c0 + j] + bS[c0 + j];
        float b2 = (v[j + 1] - m) * r * wS[c0 + j + 1] + bS[c0 + j + 1];
        ushort h0, l0, h1, l1; bf_split(a, h0, l0); bf_split(b2, h1, l1);
        size_t w = (size_t)((c0 + j) >> 1) * NPIX + p;
        XH[w] = (uint)h0 | ((uint)h1 << 16);
        XL[w] = (uint)l0 | ((uint)l1 << 16);
    }
}

// ---- MFMA GEMM, 2-phase pipelined, dbuf LDS, coalesced B staging, A+B prefetch ----
// Out(M,NPIX) = W(M,K) @ X(K,NPIX), 3-term bf16 hi/lo. NT = n-tile (64 or 128).
template <int NT, bool RES>
__global__ void gemm_mfma(const ushort* __restrict__ WH, const ushort* __restrict__ WL,
                          const uint* __restrict__ BpH, const uint* __restrict__ BpL,
                          const float* __restrict__ bias, const float* __restrict__ res,
                          float* __restrict__ Out, int M, int K, int ksteps) {
    constexpr int NI = NT / 32;          // per-wave n-fragments
    constexpr int TPR = NT / 4;          // threads per kpair-row (uint4 granules)
    constexpr int RPP = 1024 / NT;       // kpair rows per pass (256 thr)
    constexpr int NU = 16 / RPP;         // passes to cover 16 kpair rows
    constexpr int LDSW = NT * 21;        // words per plane per buffer (stride 21)
    __shared__ uint BhL[2][LDSW];
    __shared__ uint BlL[2][LDSW];
    __shared__ float biasS[128];
    const int N = NPIX;
    int tid = threadIdx.x;
    int m0 = blockIdx.y * 128;
    int n0 = blockIdx.x * NT;
    int l = tid & 63;
    int wid = tid >> 6;
    int wr = wid >> 1, wc = wid & 1;
    int lr = l & 15, lk = l >> 4;
    int rw = tid / TPR;                  // kpair row within pass
    int c4 = (tid % TPR) * 4;            // column (u32 granule) start

    if (tid < 128) biasS[tid] = (m0 + tid < M) ? bias[m0 + tid] : 0.f;

    float4v acc[4][NI];
    #pragma unroll
    for (int i = 0; i < 4; ++i)
        #pragma unroll
        for (int j = 0; j < NI; ++j) acc[i][j] = (float4v)0.f;

    const int Kh = K >> 1;
    uint4 sh[NU], sl[NU];
    short8v ahC[4], alC[4], ahN[4], alN[4];

    auto LOADB = [&](int ks) {
        #pragma unroll
        for (int u = 0; u < NU; ++u) {
            int r = rw + u * RPP;
            int kpg = ks * 16 + r;
            bool kin = kpg < Kh;
            int kpc = kin ? kpg : (Kh - 1);
            sh[u] = *(const uint4*)&BpH[(size_t)kpc * N + n0 + c4];
            sl[u] = *(const uint4*)&BpL[(size_t)kpc * N + n0 + c4];
            if (!kin) {
                sh[u] = make_uint4(0, 0, 0, 0);
                sl[u] = make_uint4(0, 0, 0, 0);
            }
        }
    };
    auto STOREB = [&](int buf) {
        #pragma unroll
        for (int u = 0; u < NU; ++u) {
            int r = rw + u * RPP;
            BhL[buf][(c4 + 0) * 21 + r] = sh[u].x;
            BhL[buf][(c4 + 1) * 21 + r] = sh[u].y;
            BhL[buf][(c4 + 2) * 21 + r] = sh[u].z;
            BhL[buf][(c4 + 3) * 21 + r] = sh[u].w;
            BlL[buf][(c4 + 0) * 21 + r] = sl[u].x;
            BlL[buf][(c4 + 1) * 21 + r] = sl[u].y;
            BlL[buf][(c4 + 2) * 21 + r] = sl[u].z;
            BlL[buf][(c4 + 3) * 21 + r] = sl[u].w;
        }
    };
    auto LOADA = [&](int ks, short8v (&ah)[4], short8v (&al)[4]) {
        int kk = ks * 32 + lk * 8;
        bool kok = (kk + 7) < K;
        int kc = kok ? kk : 0;
        #pragma unroll
        for (int mi = 0; mi < 4; ++mi) {
            int arow = m0 + wr * 64 + mi * 16 + lr;
            bool ok = (arow < M) && kok;
            int arc = arow < M ? arow : (M - 1);
            short8v th = *(const short8v*)&WH[(size_t)arc * K + kc];
            short8v tl = *(const short8v*)&WL[(size_t)arc * K + kc];
            short8v z = (short8v)0;
            ah[mi] = ok ? th : z;
            al[mi] = ok ? tl : z;
        }
    };

    LOADB(0);
    LOADA(0, ahC, alC);
    STOREB(0);
    __syncthreads();
    int cur = 0;

    for (int ks = 0; ks < ksteps; ++ks) {
        bool more = (ks + 1) < ksteps;
        if (more) {
            LOADB(ks + 1);               // issue B first (oldest in vmcnt queue)
            LOADA(ks + 1, ahN, alN);     // A after: stays in flight across STOREB
        }
        short8v bh[NI], bl[NI];
        #pragma unroll
        for (int ni = 0; ni < NI; ++ni) {
            int brow = wc * (NI * 16) + ni * 16 + lr;
            bh[ni] = *(const short8v*)&BhL[cur][brow * 21 + lk * 4];
            bl[ni] = *(const short8v*)&BlL[cur][brow * 21 + lk * 4];
        }
        #pragma unroll
        for (int mi = 0; mi < 4; ++mi)
            #pragma unroll
            for (int ni = 0; ni < NI; ++ni) {
                acc[mi][ni] = __builtin_amdgcn_mfma_f32_16x16x32_bf16(ahC[mi], bh[ni], acc[mi][ni], 0, 0, 0);
                acc[mi][ni] = __builtin_amdgcn_mfma_f32_16x16x32_bf16(ahC[mi], bl[ni], acc[mi][ni], 0, 0, 0);
                acc[mi][ni] = __builtin_amdgcn_mfma_f32_16x16x32_bf16(alC[mi], bh[ni], acc[mi][ni], 0, 0, 0);
            }
        if (more) {
            STOREB(cur ^ 1);             // waits vmcnt for B only; A still in flight
            __syncthreads();
            cur ^= 1;
            #pragma unroll
            for (int mi = 0; mi < 4; ++mi) { ahC[mi] = ahN[mi]; alC[mi] = alN[mi]; }
        }
    }

    int lr4 = lk * 4;
    #pragma unroll
    for (int mi = 0; mi < 4; ++mi) {
        #pragma unroll
        for (int ni = 0; ni < NI; ++ni) {
            int rloc = wr * 64 + mi * 16 + lr4;
            int col = n0 + wc * (NI * 16) + ni * 16 + lr;
            #pragma unroll
            for (int r = 0; r < 4; ++r) {
                int row = m0 + rloc + r;
                if (row < M) {
                    float v = acc[mi][ni][r] + biasS[rloc + r];
                    size_t o = (size_t)row * N + col;
                    if (RES) v += res[o];
                    Out[o] = v;
                }
            }
        }
    }
}

// ---- depthwise 3x3 (SAME) tiled in LDS, fused sum-of-squares for q,k ----
__global__ void dwconv_sumsq(const float* __restrict__ in, const float* __restrict__ w9,
                             const float* __restrict__ bias, float* __restrict__ out,
                             float* __restrict__ ssq, float* __restrict__ ssk) {
    // grid = 768*4: ch = bid>>2, rt = bid&3; tile 32 rows x 128 cols
    __shared__ float T[34][132];
    __shared__ float red[256];
    int bid = blockIdx.x;
    int ch = bid >> 2, rt = bid & 3;
    int g0 = rt * 32;
    int t = threadIdx.x;
    const float* src = in + (size_t)ch * NPIX;
    int c4 = (t & 31) * 4;
    for (int rr = t >> 5; rr < 34; rr += 8) {
        int grow = g0 - 1 + rr;
        float4 v = make_float4(0.f, 0.f, 0.f, 0.f);
        if (grow >= 0 && grow < 128) v = *(const float4*)&src[grow * 128 + c4];
        *(float4*)&T[rr][c4 + 1] = v;
    }
    if (t < 34) { T[t][0] = 0.f; T[t][129] = 0.f; }
    float wgt[9];
    #pragma unroll
    for (int i = 0; i < 9; ++i) wgt[i] = w9[ch * 9 + i];
    float bi = bias[ch];
    __syncthreads();
    int w = t & 127;
    int jb = (t >> 7) * 16;
    float a0 = T[jb][w], a1 = T[jb][w + 1], a2 = T[jb][w + 2];
    float b0 = T[jb + 1][w], b1 = T[jb + 1][w + 1], b2 = T[jb + 1][w + 2];
    float sq = 0.f;
    float* dst = out + (size_t)ch * NPIX + (g0 + jb) * 128 + w;
    #pragma unroll
    for (int i = 0; i < 16; ++i) {
        float c0 = T[jb + i + 2][w], c1 = T[jb + i + 2][w + 1], c2 = T[jb + i + 2][w + 2];
        float acc = bi + wgt[0] * a0 + wgt[1] * a1 + wgt[2] * a2
                       + wgt[3] * b0 + wgt[4] * b1 + wgt[5] * b2
                       + wgt[6] * c0 + wgt[7] * c1 + wgt[8] * c2;
        dst[i * 128] = acc;
        sq += acc * acc;
        a0 = b0; a1 = b1; a2 = b2; b0 = c0; b1 = c1; b2 = c2;
    }
    if (ch < 512) {
        red[t] = sq;
        __syncthreads();
        for (int st = 128; st > 0; st >>= 1) {
            if (t < st) red[t] += red[t + st];
            __syncthreads();
        }
        if (t == 0) {
            float* d2 = (ch < DIM) ? &ssq[ch] : &ssk[ch - DIM];
            atomicAdd(d2, red[0]);
        }
    }
}

// ---- Gram: G[h,c,d] = sum_n q[c,n]*k[d,n] ----
__global__ void gram_kernel(const float* __restrict__ qkv, float* __restrict__ G) {
    int hH = blockIdx.x;
    int n0 = blockIdx.y * 512;
    __shared__ float qs[32][68];
    __shared__ float ks[32][68];
    int tid = threadIdx.x;
    int c = tid >> 3;
    int lo = (tid & 7) * 8;
    int dbase = tid & 7;
    const float* qbase = qkv + ((size_t)hH * HD + c) * NPIX;
    const float* kbase = qbase + (size_t)DIM * NPIX;
    float acc[4] = {0.f, 0.f, 0.f, 0.f};
    for (int t0 = 0; t0 < 512; t0 += 64) {
        __syncthreads();
        *(float4*)&qs[c][lo]     = *(const float4*)&qbase[n0 + t0 + lo];
        *(float4*)&qs[c][lo + 4] = *(const float4*)&qbase[n0 + t0 + lo + 4];
        *(float4*)&ks[c][lo]     = *(const float4*)&kbase[n0 + t0 + lo];
        *(float4*)&ks[c][lo + 4] = *(const float4*)&kbase[n0 + t0 + lo + 4];
        __syncthreads();
        for (int t = 0; t < 64; ++t) {
            float qv = qs[c][t];
            #pragma unroll
            for (int j = 0; j < 4; ++j) acc[j] += qv * ks[dbase + 8 * j][t];
        }
    }
    float* Gb = G + hH * 1024 + c * 32;
    #pragma unroll
    for (int j = 0; j < 4; ++j) atomicAdd(&Gb[dbase + 8 * j], acc[j]);
}

// ---- softmax over d with l2-norm scaling and temperature ----
__global__ void attn_softmax(const float* __restrict__ G, const float* __restrict__ ssq,
                             const float* __restrict__ ssk, const float* __restrict__ temp,
                             float* __restrict__ A) {
    int hH = blockIdx.x;
    int tid = threadIdx.x;
    int c = tid >> 5, d = tid & 31;
    float nq = fmaxf(sqrtf(ssq[hH * HD + c]), 1e-12f);
    float nk = fmaxf(sqrtf(ssk[hH * HD + d]), 1e-12f);
    float v = G[hH * 1024 + c * 32 + d] / (nq * nk) * temp[hH];
    float m = v;
    #pragma unroll
    for (int s = 1; s < 32; s <<= 1) m = fmaxf(m, __shfl_xor(m, s, 32));
    float e = expf(v - m);
    float ssum = e;
    #pragma unroll
    for (int s = 1; s < 32; s <<= 1) ssum += __shfl_xor(ssum, s, 32);
    A[hH * 1024 + c * 32 + d] = e / ssum;
}

// ---- PV: writes paired bf16 hi/lo ----
__global__ void pv_kernel(const float* __restrict__ A, const float* __restrict__ qkv,
                          uint* __restrict__ VH, uint* __restrict__ VL) {
    int hH = blockIdx.x;
    int n = blockIdx.y * 256 + threadIdx.x;
    __shared__ float As[1024];
    for (int i = threadIdx.x; i < 1024; i += 256) As[i] = A[hH * 1024 + i];
    __syncthreads();
    const float* vbase = qkv + ((size_t)(512 + hH * HD)) * NPIX + n;
    float vv[32];
    #pragma unroll
    for (int d = 0; d < 32; ++d) vv[d] = vbase[(size_t)d * NPIX];
    #pragma unroll
    for (int cc = 0; cc < 32; cc += 2) {
        float a0 = 0.f, a1 = 0.f;
        #pragma unroll
        for (int d = 0; d < 32; ++d) {
            a0 += As[cc * 32 + d] * vv[d];
            a1 += As[cc * 32 + 32 + d] * vv[d];
        }
        ushort h0, l0, h1, l1; bf_split(a0, h0, l0); bf_split(a1, h1, l1);
        size_t w = (size_t)((hH * HD + cc) >> 1) * NPIX + n;
        VH[w] = (uint)h0 | ((uint)h1 << 16);
        VL[w] = (uint)l0 | ((uint)l1 << 16);
    }
}

// ---- FFN depthwise 3x3 + gelu gating, tiled in LDS, paired bf16 out ----
__global__ void dwgate(const float* __restrict__ in, const float* __restrict__ w9,
                       const float* __restrict__ bias, uint* __restrict__ GH,
                       uint* __restrict__ GL) {
    __shared__ float T[4][18][132];
    int bid = blockIdx.x;
    int cp = bid >> 3, rt = bid & 7;
    int c0 = cp * 2;
    int g0 = rt * 16;
    int t = threadIdx.x;
    for (int idx = t; idx < 4 * 18 * 32; idx += 256) {
        int pl = idx / 576;
        int rem = idx - pl * 576;
        int rr = rem >> 5;
        int cc4 = (rem & 31) * 4;
        int ch = c0 + (pl & 1) + (pl >> 1) * HID;
        int grow = g0 - 1 + rr;
        float4 v = make_float4(0.f, 0.f, 0.f, 0.f);
        if (grow >= 0 && grow < 128)
            v = *(const float4*)&in[(size_t)ch * NPIX + grow * 128 + cc4];
        *(float4*)&T[pl][rr][cc4 + 1] = v;
    }
    if (t < 72) {
        int pl = t / 18, rr = t % 18;
        T[pl][rr][0] = 0.f; T[pl][rr][129] = 0.f;
    }
    float wg[4][9]; float bs[4];
    #pragma unroll
    for (int p = 0; p < 4; ++p) {
        int ch = c0 + (p & 1) + (p >> 1) * HID;
        bs[p] = bias[ch];
        #pragma unroll
        for (int i = 0; i < 9; ++i) wg[p][i] = w9[ch * 9 + i];
    }
    __syncthreads();
    int w = t & 127;
    int jb = (t >> 7) * 8;
    float A[4][3], B[4][3];
    #pragma unroll
    for (int p = 0; p < 4; ++p) {
        A[p][0] = T[p][jb][w];     A[p][1] = T[p][jb][w + 1];     A[p][2] = T[p][jb][w + 2];
        B[p][0] = T[p][jb + 1][w]; B[p][1] = T[p][jb + 1][w + 1]; B[p][2] = T[p][jb + 1][w + 2];
    }
    size_t wbase = (size_t)cp * NPIX + (g0 + jb) * 128 + w;
    #pragma unroll
    for (int i = 0; i < 8; ++i) {
        float o[4];
        #pragma unroll
        for (int p = 0; p < 4; ++p) {
            float cA = T[p][jb + i + 2][w], cB = T[p][jb + i + 2][w + 1], cC = T[p][jb + i + 2][w + 2];
            o[p] = bs[p] + wg[p][0] * A[p][0] + wg[p][1] * A[p][1] + wg[p][2] * A[p][2]
                         + wg[p][3] * B[p][0] + wg[p][4] * B[p][1] + wg[p][5] * B[p][2]
                         + wg[p][6] * cA + wg[p][7] * cB + wg[p][8] * cC;
            A[p][0] = B[p][0]; A[p][1] = B[p][1]; A[p][2] = B[p][2];
            B[p][0] = cA; B[p][1] = cB; B[p][2] = cC;
        }
        float g0f = 0.5f * o[2] * (1.0f + erff(o[2] * 0.70710678118654752f));
        float g1f = 0.5f * o[3] * (1.0f + erff(o[3] * 0.70710678118654752f));
        float r0 = o[0] * g0f, r1 = o[1] * g1f;
        ushort h0, l0, h1, l1; bf_split(r0, h0, l0); bf_split(r1, h1, l1);
        GH[wbase + i * 128] = (uint)h0 | ((uint)h1 << 16);
        GL[wbase + i * 128] = (uint)l0 | ((uint)l1 << 16);
    }
}

extern "C" void kernel_launch(void* const* d_in, const int* in_sizes, int n_in,
                              void* d_out, int out_size, void* d_ws, size_t ws_size,
                              hipStream_t stream) {
    const float* x        = (const float*)d_in[0];
    const float* n1w      = (const float*)d_in[1];
    const float* n1b      = (const float*)d_in[2];
    const float* temp     = (const float*)d_in[3];
    const float* qkv_w    = (const float*)d_in[4];
    const float* qkv_b    = (const float*)d_in[5];
    const float* qkv_dw_w = (const float*)d_in[6];
    const float* qkv_dw_b = (const float*)d_in[7];
    const float* po_w     = (const float*)d_in[8];
    const float* po_b     = (const float*)d_in[9];
    const float* n2w      = (const float*)d_in[10];
    const float* n2b      = (const float*)d_in[11];
    const float* pin_w    = (const float*)d_in[12];
    const float* pin_b    = (const float*)d_in[13];
    const float* dw_w     = (const float*)d_in[14];
    const float* dw_b     = (const float*)d_in[15];
    const float* pout_w   = (const float*)d_in[16];
    const float* pout_b   = (const float*)d_in[17];
    float* out = (float*)d_out;

    // ---- workspace arena (~193 MB) ----
    char* ws = (char*)d_ws;
    float* R0 = (float*)ws;                       // qkv fp32: 50331648 B
    char*  R1c = ws + 50331648;                   // multi-use region, 50331648 B
    float* R1 = (float*)R1c;                      // dwconv out fp32
    float* R2 = (float*)(ws + 100663296);         // pin out fp32: 89128960 B
    char*  wb = ws + 189792256;
    ushort* WqkvH = (ushort*)wb;
    ushort* WqkvL = WqkvH + 196608;
    ushort* WpoH  = WqkvL + 196608;
    ushort* WpoL  = WpoH + 65536;
    ushort* WpinH = WpoL + 65536;
    ushort* WpinL = WpinH + 348160;
    ushort* WpoutH = WpinL + 348160;
    ushort* WpoutL = WpoutH + 174080;
    float* G     = (float*)(wb + 3137536);
    float* ssq   = G + 8192;
    float* ssk   = ssq + 256;
    float* attnA = ssk + 256;
    uint* XHp = (uint*)R1c;
    uint* XLp = XHp + 2097152;
    uint* VHp = (uint*)R1c;
    uint* VLp = XLp;
    uint* GHp = (uint*)R1c;
    uint* GLp = GHp + 5570560;

    convert_weights<<<3064, 256, 0, stream>>>(qkv_w, po_w, pin_w, pout_w,
                                              WqkvH, WqkvL, WpoH, WpoL,
                                              WpinH, WpinL, WpoutH, WpoutL);

    for (int b = 0; b < BATCH; ++b) {
        const float* xb = x + (size_t)b * DIM * NPIX;
        float* outb = out + (size_t)b * DIM * NPIX;

        // ---- attention branch ----
        ln_fused<<<256, 256, 0, stream>>>(xb, n1w, n1b, XHp, XLp);
        gemm_mfma<128, false><<<dim3(128, 6), 256, 0, stream>>>(
            WqkvH, WqkvL, XHp, XLp, qkv_b, nullptr, R0, CHQKV, DIM, 8);
        zero_kernel<<<34, 256, 0, stream>>>(G, 8704);
        dwconv_sumsq<<<CHQKV * 4, 256, 0, stream>>>(R0, qkv_dw_w, qkv_dw_b, R1, ssq, ssk);
        gram_kernel<<<dim3(8, 32), 256, 0, stream>>>(R1, G);
        attn_softmax<<<8, 1024, 0, stream>>>(G, ssq, ssk, temp, attnA);
        pv_kernel<<<dim3(8, 64), 256, 0, stream>>>(attnA, R1, VHp, VLp);
        gemm_mfma<64, true><<<dim3(256, 2), 256, 0, stream>>>(
            WpoH, WpoL, VHp, VLp, po_b, xb, outb, DIM, DIM, 8);

        // ---- FFN branch ----
        ln_fused<<<256, 256, 0, stream>>>(outb, n2w, n2b, XHp, XLp);
        gemm_mfma<128, false><<<dim3(128, 11), 256, 0, stream>>>(
            WpinH, WpinL, XHp, XLp, pin_b, nullptr, R2, HID2, DIM, 8);
        dwgate<<<340 * 8, 256, 0, stream>>>(R2, dw_w, dw_b, GHp, GLp);
        gemm_mfma<64, true><<<dim3(256, 2), 256, 0, stream>>>(
            WpoutH, WpoutL, GHp, GLp, pout_b, outb, outb, DIM, HID, 22);
    }
}

// Round 7
// 1324.846 us; speedup vs baseline: 1.9329x; 1.9329x over previous
//
#include <hip/hip_runtime.h>
#include <hip/hip_bf16.h>

#define NPIX 16384   // 128*128
#define BATCH 4
#define DIM 256
#define HEADS 8
#define HD 32
#define CHQKV 768
#define HID 680
#define HID2 1360

typedef __attribute__((ext_vector_type(8))) short short8v;
typedef __attribute__((ext_vector_type(4))) float float4v;

__device__ __forceinline__ ushort bf_hi(float v) {
    unsigned u = __float_as_uint(v);
    u += 0x7fffu + ((u >> 16) & 1u);          // RNE to bf16
    return (ushort)(u >> 16);
}
__device__ __forceinline__ float bf_tof(ushort h) {
    return __uint_as_float(((unsigned)h) << 16);
}
__device__ __forceinline__ void bf_split(float v, ushort &h, ushort &l) {
    h = bf_hi(v);
    l = bf_hi(v - bf_tof(h));
}

__global__ void zero_kernel(float* __restrict__ p, int n) {
    int i = blockIdx.x * blockDim.x + threadIdx.x;
    if (i < n) p[i] = 0.f;
}

// ---- one-time: split all 4 weight matrices into bf16 hi/lo planes ([m][k] layout) ----
__global__ void convert_weights(const float* __restrict__ qkv_w, const float* __restrict__ po_w,
                                const float* __restrict__ pin_w, const float* __restrict__ pout_w,
                                ushort* __restrict__ qH, ushort* __restrict__ qL,
                                ushort* __restrict__ oH, ushort* __restrict__ oL,
                                ushort* __restrict__ iH, ushort* __restrict__ iL,
                                ushort* __restrict__ uH, ushort* __restrict__ uL) {
    int i = blockIdx.x * 256 + threadIdx.x;
    const float* s; ushort *dh, *dl; int off;
    if (i < 196608)      { s = qkv_w;  dh = qH; dl = qL; off = i; }
    else if (i < 262144) { s = po_w;   dh = oH; dl = oL; off = i - 196608; }
    else if (i < 610304) { s = pin_w;  dh = iH; dl = iL; off = i - 262144; }
    else if (i < 784384) { s = pout_w; dh = uH; dl = uL; off = i - 610304; }
    else return;
    ushort h, l; bf_split(s[off], h, l);
    dh[off] = h; dl[off] = l;
}

// ---- fused LN stats + apply, writing k-pair-interleaved bf16 hi/lo planes ----
__global__ void ln_fused(const float* __restrict__ x, const float* __restrict__ lw,
                         const float* __restrict__ lb, uint* __restrict__ XH,
                         uint* __restrict__ XL) {
    __shared__ float Ss[256], Ss2[256], muS[64], rsS[64], wS[256], bS[256];
    int t = threadIdx.x, px = t & 63, cg = t >> 6, c0 = cg * 64;
    int p = blockIdx.x * 64 + px;
    wS[t] = lw[t]; bS[t] = lb[t];
    float v[64]; float s = 0.f, s2 = 0.f;
    #pragma unroll
    for (int j = 0; j < 64; ++j) {
        v[j] = x[(size_t)(c0 + j) * NPIX + p];
        s += v[j]; s2 += v[j] * v[j];
    }
    Ss[t] = s; Ss2[t] = s2;
    __syncthreads();
    if (t < 64) {
        float ts = Ss[t] + Ss[t + 64] + Ss[t + 128] + Ss[t + 192];
        float t2 = Ss2[t] + Ss2[t + 64] + Ss2[t + 128] + Ss2[t + 192];
        float m = ts * (1.0f / DIM);
        float var = t2 * (1.0f / DIM) - m * m;
        muS[t] = m; rsS[t] = rsqrtf(var + 1e-5f);
    }
    __syncthreads();
    float m = muS[px], r = rsS[px];
    #pragma unroll
    for (int j = 0; j < 64; j += 2) {
        float a = (v[j] - m) * r * wS[c0 + j] + bS[c0 + j];
        float b2 = (v[j + 1] - m) * r * wS[c0 + j + 1] + bS[c0 + j + 1];
        ushort h0, l0, h1, l1; bf_split(a, h0, l0); bf_split(b2, h1, l1);
        size_t w = (size_t)((c0 + j) >> 1) * NPIX + p;
        XH[w] = (uint)h0 | ((uint)h1 << 16);
        XL[w] = (uint)l0 | ((uint)l1 << 16);
    }
}

// ---- MFMA GEMM, 2-phase pipelined, dbuf LDS, coalesced B staging ----
// Out(M,NPIX) = W(M,K) @ X(K,NPIX), 3-term bf16 hi/lo. NT = n-tile (64 or 128).
// __launch_bounds__(256,2): 256-thread blocks -> VGPR cap 256 (no 1024-wg spill trap).
template <int NT, bool RES>
__global__ __launch_bounds__(256, 2)
void gemm_mfma(const ushort* __restrict__ WH, const ushort* __restrict__ WL,
               const uint* __restrict__ BpH, const uint* __restrict__ BpL,
               const float* __restrict__ bias, const float* __restrict__ res,
               float* __restrict__ Out, int M, int K, int ksteps) {
    constexpr int NI = NT / 32;          // per-wave n-fragments
    constexpr int TPR = NT / 4;          // threads per kpair-row (uint4 granules)
    constexpr int RPP = 1024 / NT;       // kpair rows per pass (256 thr)
    constexpr int NU = 16 / RPP;         // passes to cover 16 kpair rows
    constexpr int LDSW = NT * 21;        // words per plane per buffer (stride 21)
    __shared__ uint BhL[2][LDSW];
    __shared__ uint BlL[2][LDSW];
    __shared__ float biasS[128];
    const int N = NPIX;
    int tid = threadIdx.x;
    int m0 = blockIdx.y * 128;
    int n0 = blockIdx.x * NT;
    int l = tid & 63;
    int wid = tid >> 6;
    int wr = wid >> 1, wc = wid & 1;
    int lr = l & 15, lk = l >> 4;
    int rw = tid / TPR;                  // kpair row within pass
    int c4 = (tid % TPR) * 4;            // column (u32 granule) start

    if (tid < 128) biasS[tid] = (m0 + tid < M) ? bias[m0 + tid] : 0.f;

    float4v acc[4][NI];
    #pragma unroll
    for (int i = 0; i < 4; ++i)
        #pragma unroll
        for (int j = 0; j < NI; ++j) acc[i][j] = (float4v)0.f;

    const int Kh = K >> 1;
    uint4 sh[NU], sl[NU];
    short8v ah[4], al[4];

    auto LOADB = [&](int ks) {
        #pragma unroll
        for (int u = 0; u < NU; ++u) {
            int r = rw + u * RPP;
            int kpg = ks * 16 + r;
            bool kin = kpg < Kh;
            int kpc = kin ? kpg : (Kh - 1);
            sh[u] = *(const uint4*)&BpH[(size_t)kpc * N + n0 + c4];
            sl[u] = *(const uint4*)&BpL[(size_t)kpc * N + n0 + c4];
            if (!kin) {
                sh[u] = make_uint4(0, 0, 0, 0);
                sl[u] = make_uint4(0, 0, 0, 0);
            }
        }
    };
    auto STOREB = [&](int buf) {
        #pragma unroll
        for (int u = 0; u < NU; ++u) {
            int r = rw + u * RPP;
            BhL[buf][(c4 + 0) * 21 + r] = sh[u].x;
            BhL[buf][(c4 + 1) * 21 + r] = sh[u].y;
            BhL[buf][(c4 + 2) * 21 + r] = sh[u].z;
            BhL[buf][(c4 + 3) * 21 + r] = sh[u].w;
            BlL[buf][(c4 + 0) * 21 + r] = sl[u].x;
            BlL[buf][(c4 + 1) * 21 + r] = sl[u].y;
            BlL[buf][(c4 + 2) * 21 + r] = sl[u].z;
            BlL[buf][(c4 + 3) * 21 + r] = sl[u].w;
        }
    };
    auto LOADA = [&](int ks) {
        int kk = ks * 32 + lk * 8;
        bool kok = (kk + 7) < K;
        int kc = kok ? kk : 0;
        #pragma unroll
        for (int mi = 0; mi < 4; ++mi) {
            int arow = m0 + wr * 64 + mi * 16 + lr;
            bool ok = (arow < M) && kok;
            int arc = arow < M ? arow : (M - 1);
            short8v th = *(const short8v*)&WH[(size_t)arc * K + kc];
            short8v tl = *(const short8v*)&WL[(size_t)arc * K + kc];
            short8v z = (short8v)0;
            ah[mi] = ok ? th : z;
            al[mi] = ok ? tl : z;
        }
    };

    LOADB(0);
    STOREB(0);
    __syncthreads();
    int cur = 0;

    for (int ks = 0; ks < ksteps; ++ks) {
        bool more = (ks + 1) < ksteps;
        if (more) LOADB(ks + 1);          // prefetch next B tile into regs
        LOADA(ks);                        // A from L2 (weights resident); ah/al die at MFMA
        short8v bh[NI], bl[NI];
        #pragma unroll
        for (int ni = 0; ni < NI; ++ni) {
            int brow = wc * (NI * 16) + ni * 16 + lr;
            bh[ni] = *(const short8v*)&BhL[cur][brow * 21 + lk * 4];
            bl[ni] = *(const short8v*)&BlL[cur][brow * 21 + lk * 4];
        }
        #pragma unroll
        for (int mi = 0; mi < 4; ++mi)
            #pragma unroll
            for (int ni = 0; ni < NI; ++ni) {
                acc[mi][ni] = __builtin_amdgcn_mfma_f32_16x16x32_bf16(ah[mi], bh[ni], acc[mi][ni], 0, 0, 0);
                acc[mi][ni] = __builtin_amdgcn_mfma_f32_16x16x32_bf16(ah[mi], bl[ni], acc[mi][ni], 0, 0, 0);
                acc[mi][ni] = __builtin_amdgcn_mfma_f32_16x16x32_bf16(al[mi], bh[ni], acc[mi][ni], 0, 0, 0);
            }
        if (more) {
            STOREB(cur ^ 1);              // drains B prefetch into alternate buffer
            __syncthreads();
            cur ^= 1;
        }
    }

    int lr4 = lk * 4;
    #pragma unroll
    for (int mi = 0; mi < 4; ++mi) {
        #pragma unroll
        for (int ni = 0; ni < NI; ++ni) {
            int rloc = wr * 64 + mi * 16 + lr4;
            int col = n0 + wc * (NI * 16) + ni * 16 + lr;
            #pragma unroll
            for (int r = 0; r < 4; ++r) {
                int row = m0 + rloc + r;
                if (row < M) {
                    float v = acc[mi][ni][r] + biasS[rloc + r];
                    size_t o = (size_t)row * N + col;
                    if (RES) v += res[o];
                    Out[o] = v;
                }
            }
        }
    }
}

// ---- depthwise 3x3 (SAME) tiled in LDS, fused sum-of-squares for q,k ----
__global__ void dwconv_sumsq(const float* __restrict__ in, const float* __restrict__ w9,
                             const float* __restrict__ bias, float* __restrict__ out,
                             float* __restrict__ ssq, float* __restrict__ ssk) {
    // grid = 768*4: ch = bid>>2, rt = bid&3; tile 32 rows x 128 cols
    __shared__ float T[34][132];
    __shared__ float red[256];
    int bid = blockIdx.x;
    int ch = bid >> 2, rt = bid & 3;
    int g0 = rt * 32;
    int t = threadIdx.x;
    const float* src = in + (size_t)ch * NPIX;
    int c4 = (t & 31) * 4;
    for (int rr = t >> 5; rr < 34; rr += 8) {
        int grow = g0 - 1 + rr;
        float4 v = make_float4(0.f, 0.f, 0.f, 0.f);
        if (grow >= 0 && grow < 128) v = *(const float4*)&src[grow * 128 + c4];
        *(float4*)&T[rr][c4 + 1] = v;
    }
    if (t < 34) { T[t][0] = 0.f; T[t][129] = 0.f; }
    float wgt[9];
    #pragma unroll
    for (int i = 0; i < 9; ++i) wgt[i] = w9[ch * 9 + i];
    float bi = bias[ch];
    __syncthreads();
    int w = t & 127;
    int jb = (t >> 7) * 16;
    float a0 = T[jb][w], a1 = T[jb][w + 1], a2 = T[jb][w + 2];
    float b0 = T[jb + 1][w], b1 = T[jb + 1][w + 1], b2 = T[jb + 1][w + 2];
    float sq = 0.f;
    float* dst = out + (size_t)ch * NPIX + (g0 + jb) * 128 + w;
    #pragma unroll
    for (int i = 0; i < 16; ++i) {
        float c0 = T[jb + i + 2][w], c1 = T[jb + i + 2][w + 1], c2 = T[jb + i + 2][w + 2];
        float acc = bi + wgt[0] * a0 + wgt[1] * a1 + wgt[2] * a2
                       + wgt[3] * b0 + wgt[4] * b1 + wgt[5] * b2
                       + wgt[6] * c0 + wgt[7] * c1 + wgt[8] * c2;
        dst[i * 128] = acc;
        sq += acc * acc;
        a0 = b0; a1 = b1; a2 = b2; b0 = c0; b1 = c1; b2 = c2;
    }
    if (ch < 512) {
        red[t] = sq;
        __syncthreads();
        for (int st = 128; st > 0; st >>= 1) {
            if (t < st) red[t] += red[t + st];
            __syncthreads();
        }
        if (t == 0) {
            float* d2 = (ch < DIM) ? &ssq[ch] : &ssk[ch - DIM];
            atomicAdd(d2, red[0]);
        }
    }
}

// ---- Gram: G[h,c,d] = sum_n q[c,n]*k[d,n] ----
__global__ void gram_kernel(const float* __restrict__ qkv, float* __restrict__ G) {
    int hH = blockIdx.x;
    int n0 = blockIdx.y * 512;
    __shared__ float qs[32][68];
    __shared__ float ks[32][68];
    int tid = threadIdx.x;
    int c = tid >> 3;
    int lo = (tid & 7) * 8;
    int dbase = tid & 7;
    const float* qbase = qkv + ((size_t)hH * HD + c) * NPIX;
    const float* kbase = qbase + (size_t)DIM * NPIX;
    float acc[4] = {0.f, 0.f, 0.f, 0.f};
    for (int t0 = 0; t0 < 512; t0 += 64) {
        __syncthreads();
        *(float4*)&qs[c][lo]     = *(const float4*)&qbase[n0 + t0 + lo];
        *(float4*)&qs[c][lo + 4] = *(const float4*)&qbase[n0 + t0 + lo + 4];
        *(float4*)&ks[c][lo]     = *(const float4*)&kbase[n0 + t0 + lo];
        *(float4*)&ks[c][lo + 4] = *(const float4*)&kbase[n0 + t0 + lo + 4];
        __syncthreads();
        for (int t = 0; t < 64; ++t) {
            float qv = qs[c][t];
            #pragma unroll
            for (int j = 0; j < 4; ++j) acc[j] += qv * ks[dbase + 8 * j][t];
        }
    }
    float* Gb = G + hH * 1024 + c * 32;
    #pragma unroll
    for (int j = 0; j < 4; ++j) atomicAdd(&Gb[dbase + 8 * j], acc[j]);
}

// ---- softmax over d with l2-norm scaling and temperature ----
__global__ void attn_softmax(const float* __restrict__ G, const float* __restrict__ ssq,
                             const float* __restrict__ ssk, const float* __restrict__ temp,
                             float* __restrict__ A) {
    int hH = blockIdx.x;
    int tid = threadIdx.x;
    int c = tid >> 5, d = tid & 31;
    float nq = fmaxf(sqrtf(ssq[hH * HD + c]), 1e-12f);
    float nk = fmaxf(sqrtf(ssk[hH * HD + d]), 1e-12f);
    float v = G[hH * 1024 + c * 32 + d] / (nq * nk) * temp[hH];
    float m = v;
    #pragma unroll
    for (int s = 1; s < 32; s <<= 1) m = fmaxf(m, __shfl_xor(m, s, 32));
    float e = expf(v - m);
    float ssum = e;
    #pragma unroll
    for (int s = 1; s < 32; s <<= 1) ssum += __shfl_xor(ssum, s, 32);
    A[hH * 1024 + c * 32 + d] = e / ssum;
}

// ---- PV: writes paired bf16 hi/lo ----
__global__ void pv_kernel(const float* __restrict__ A, const float* __restrict__ qkv,
                          uint* __restrict__ VH, uint* __restrict__ VL) {
    int hH = blockIdx.x;
    int n = blockIdx.y * 256 + threadIdx.x;
    __shared__ float As[1024];
    for (int i = threadIdx.x; i < 1024; i += 256) As[i] = A[hH * 1024 + i];
    __syncthreads();
    const float* vbase = qkv + ((size_t)(512 + hH * HD)) * NPIX + n;
    float vv[32];
    #pragma unroll
    for (int d = 0; d < 32; ++d) vv[d] = vbase[(size_t)d * NPIX];
    #pragma unroll
    for (int cc = 0; cc < 32; cc += 2) {
        float a0 = 0.f, a1 = 0.f;
        #pragma unroll
        for (int d = 0; d < 32; ++d) {
            a0 += As[cc * 32 + d] * vv[d];
            a1 += As[cc * 32 + 32 + d] * vv[d];
        }
        ushort h0, l0, h1, l1; bf_split(a0, h0, l0); bf_split(a1, h1, l1);
        size_t w = (size_t)((hH * HD + cc) >> 1) * NPIX + n;
        VH[w] = (uint)h0 | ((uint)h1 << 16);
        VL[w] = (uint)l0 | ((uint)l1 << 16);
    }
}

// ---- FFN depthwise 3x3 + gelu gating, tiled in LDS, paired bf16 out ----
__global__ void dwgate(const float* __restrict__ in, const float* __restrict__ w9,
                       const float* __restrict__ bias, uint* __restrict__ GH,
                       uint* __restrict__ GL) {
    __shared__ float T[4][18][132];
    int bid = blockIdx.x;
    int cp = bid >> 3, rt = bid & 7;
    int c0 = cp * 2;
    int g0 = rt * 16;
    int t = threadIdx.x;
    for (int idx = t; idx < 4 * 18 * 32; idx += 256) {
        int pl = idx / 576;
        int rem = idx - pl * 576;
        int rr = rem >> 5;
        int cc4 = (rem & 31) * 4;
        int ch = c0 + (pl & 1) + (pl >> 1) * HID;
        int grow = g0 - 1 + rr;
        float4 v = make_float4(0.f, 0.f, 0.f, 0.f);
        if (grow >= 0 && grow < 128)
            v = *(const float4*)&in[(size_t)ch * NPIX + grow * 128 + cc4];
        *(float4*)&T[pl][rr][cc4 + 1] = v;
    }
    if (t < 72) {
        int pl = t / 18, rr = t % 18;
        T[pl][rr][0] = 0.f; T[pl][rr][129] = 0.f;
    }
    float wg[4][9]; float bs[4];
    #pragma unroll
    for (int p = 0; p < 4; ++p) {
        int ch = c0 + (p & 1) + (p >> 1) * HID;
        bs[p] = bias[ch];
        #pragma unroll
        for (int i = 0; i < 9; ++i) wg[p][i] = w9[ch * 9 + i];
    }
    __syncthreads();
    int w = t & 127;
    int jb = (t >> 7) * 8;
    float A[4][3], B[4][3];
    #pragma unroll
    for (int p = 0; p < 4; ++p) {
        A[p][0] = T[p][jb][w];     A[p][1] = T[p][jb][w + 1];     A[p][2] = T[p][jb][w + 2];
        B[p][0] = T[p][jb + 1][w]; B[p][1] = T[p][jb + 1][w + 1]; B[p][2] = T[p][jb + 1][w + 2];
    }
    size_t wbase = (size_t)cp * NPIX + (g0 + jb) * 128 + w;
    #pragma unroll
    for (int i = 0; i < 8; ++i) {
        float o[4];
        #pragma unroll
        for (int p = 0; p < 4; ++p) {
            float cA = T[p][jb + i + 2][w], cB = T[p][jb + i + 2][w + 1], cC = T[p][jb + i + 2][w + 2];
            o[p] = bs[p] + wg[p][0] * A[p][0] + wg[p][1] * A[p][1] + wg[p][2] * A[p][2]
                         + wg[p][3] * B[p][0] + wg[p][4] * B[p][1] + wg[p][5] * B[p][2]
                         + wg[p][6] * cA + wg[p][7] * cB + wg[p][8] * cC;
            A[p][0] = B[p][0]; A[p][1] = B[p][1]; A[p][2] = B[p][2];
            B[p][0] = cA; B[p][1] = cB; B[p][2] = cC;
        }
        float g0f = 0.5f * o[2] * (1.0f + erff(o[2] * 0.70710678118654752f));
        float g1f = 0.5f * o[3] * (1.0f + erff(o[3] * 0.70710678118654752f));
        float r0 = o[0] * g0f, r1 = o[1] * g1f;
        ushort h0, l0, h1, l1; bf_split(r0, h0, l0); bf_split(r1, h1, l1);
        GH[wbase + i * 128] = (uint)h0 | ((uint)h1 << 16);
        GL[wbase + i * 128] = (uint)l0 | ((uint)l1 << 16);
    }
}

extern "C" void kernel_launch(void* const* d_in, const int* in_sizes, int n_in,
                              void* d_out, int out_size, void* d_ws, size_t ws_size,
                              hipStream_t stream) {
    const float* x        = (const float*)d_in[0];
    const float* n1w      = (const float*)d_in[1];
    const float* n1b      = (const float*)d_in[2];
    const float* temp     = (const float*)d_in[3];
    const float* qkv_w    = (const float*)d_in[4];
    const float* qkv_b    = (const float*)d_in[5];
    const float* qkv_dw_w = (const float*)d_in[6];
    const float* qkv_dw_b = (const float*)d_in[7];
    const float* po_w     = (const float*)d_in[8];
    const float* po_b     = (const float*)d_in[9];
    const float* n2w      = (const float*)d_in[10];
    const float* n2b      = (const float*)d_in[11];
    const float* pin_w    = (const float*)d_in[12];
    const float* pin_b    = (const float*)d_in[13];
    const float* dw_w     = (const float*)d_in[14];
    const float* dw_b     = (const float*)d_in[15];
    const float* pout_w   = (const float*)d_in[16];
    const float* pout_b   = (const float*)d_in[17];
    float* out = (float*)d_out;

    // ---- workspace arena (~193 MB) ----
    char* ws = (char*)d_ws;
    float* R0 = (float*)ws;                       // qkv fp32: 50331648 B
    char*  R1c = ws + 50331648;                   // multi-use region, 50331648 B
    float* R1 = (float*)R1c;                      // dwconv out fp32
    float* R2 = (float*)(ws + 100663296);         // pin out fp32: 89128960 B
    char*  wb = ws + 189792256;
    ushort* WqkvH = (ushort*)wb;
    ushort* WqkvL = WqkvH + 196608;
    ushort* WpoH  = WqkvL + 196608;
    ushort* WpoL  = WpoH + 65536;
    ushort* WpinH = WpoL + 65536;
    ushort* WpinL = WpinH + 348160;
    ushort* WpoutH = WpinL + 348160;
    ushort* WpoutL = WpoutH + 174080;
    float* G     = (float*)(wb + 3137536);
    float* ssq   = G + 8192;
    float* ssk   = ssq + 256;
    float* attnA = ssk + 256;
    uint* XHp = (uint*)R1c;
    uint* XLp = XHp + 2097152;
    uint* VHp = (uint*)R1c;
    uint* VLp = XLp;
    uint* GHp = (uint*)R1c;
    uint* GLp = GHp + 5570560;

    convert_weights<<<3064, 256, 0, stream>>>(qkv_w, po_w, pin_w, pout_w,
                                              WqkvH, WqkvL, WpoH, WpoL,
                                              WpinH, WpinL, WpoutH, WpoutL);

    for (int b = 0; b < BATCH; ++b) {
        const float* xb = x + (size_t)b * DIM * NPIX;
        float* outb = out + (size_t)b * DIM * NPIX;

        // ---- attention branch ----
        ln_fused<<<256, 256, 0, stream>>>(xb, n1w, n1b, XHp, XLp);
        gemm_mfma<128, false><<<dim3(128, 6), 256, 0, stream>>>(
            WqkvH, WqkvL, XHp, XLp, qkv_b, nullptr, R0, CHQKV, DIM, 8);
        zero_kernel<<<34, 256, 0, stream>>>(G, 8704);
        dwconv_sumsq<<<CHQKV * 4, 256, 0, stream>>>(R0, qkv_dw_w, qkv_dw_b, R1, ssq, ssk);
        gram_kernel<<<dim3(8, 32), 256, 0, stream>>>(R1, G);
        attn_softmax<<<8, 1024, 0, stream>>>(G, ssq, ssk, temp, attnA);
        pv_kernel<<<dim3(8, 64), 256, 0, stream>>>(attnA, R1, VHp, VLp);
        gemm_mfma<64, true><<<dim3(256, 2), 256, 0, stream>>>(
            WpoH, WpoL, VHp, VLp, po_b, xb, outb, DIM, DIM, 8);

        // ---- FFN branch ----
        ln_fused<<<256, 256, 0, stream>>>(outb, n2w, n2b, XHp, XLp);
        gemm_mfma<128, false><<<dim3(128, 11), 256, 0, stream>>>(
            WpinH, WpinL, XHp, XLp, pin_b, nullptr, R2, HID2, DIM, 8);
        dwgate<<<340 * 8, 256, 0, stream>>>(R2, dw_w, dw_b, GHp, GLp);
        gemm_mfma<64, true><<<dim3(256, 2), 256, 0, stream>>>(
            WpoutH, WpoutL, GHp, GLp, pout_b, outb, outb, DIM, HID, 22);
    }
}